// Round 4
// baseline (133.161 us; speedup 1.0000x reference)
//
#include <hip/hip_runtime.h>

typedef __bf16 bf16_t;
typedef __attribute__((ext_vector_type(8))) __bf16 bf16x8;
typedef __attribute__((ext_vector_type(4))) float f32x4;
typedef __attribute__((ext_vector_type(8))) unsigned short ushort8;

#define QF   64
#define GG   120
#define HID  128
#define NACT 20
#define BTOT 2048   // B*T

// ---- workspace layout (bytes) ----
#define WEFFH_OFF 0u          // 120*128*64 bf16 [u][h][r] = 1,966,080
#define WEFFL_OFF 1966080u
#define XH_OFF    3932160u    // 2048*64 bf16 = 262,144
#define XL_OFF    4194304u
#define W1TH_OFF  4456448u    // 128*128 bf16 [n][k] = 32,768
#define W1TL_OFF  4489216u
#define MISC_OFF  4521984u    // bmean[128], wmean[128], cb (1088 reserved)
#define CAYL_OFF  4523072u    // 120*120 i32 = 57,600
#define FPT_OFF   4580672u    // 120*64 i32 = 30,720 (featperm table)
#define S4_OFF    4611392u    // 24 i32 (96)
#define CREP_OFF  4611488u    // 5 i32 (pad 32)
#define UBYC_OFF  4611520u    // 20*6 i32 (pad 576)
#define ABUF_OFF  4612096u    // 120*64*128 f32 = 3,932,160 (A-stage)
#define M_OFF     ABUF_OFF    // m[120][2048] f32 aliases ABUF (dead by then)
// end: 8,544,256

__device__ __forceinline__ unsigned short f2bf(float f) {
    unsigned int u = __float_as_uint(f);
    unsigned int r = u + 0x7fffu + ((u >> 16) & 1u);
    return (unsigned short)(r >> 16);
}
__device__ __forceinline__ float bf2f(unsigned short h) {
    return __uint_as_float(((unsigned int)h) << 16);
}
__device__ __forceinline__ void keepv(f32x4& v) { asm volatile("" : "+v"(v)); }

__device__ __forceinline__ void idx_to_perm(int i, int p[5]) {
    int avail[5] = {0, 1, 2, 3, 4};
    const int f[4] = {24, 6, 2, 1};
    for (int k = 0; k < 4; ++k) {
        int d = i / f[k]; i %= f[k];
        p[k] = avail[d];
        for (int j = d; j < 4 - k; ++j) avail[j] = avail[j + 1];
    }
    p[4] = avail[0];
}

__device__ __forceinline__ int perm_to_idx(const int p[5]) {
    const int f[4] = {24, 6, 2, 1};
    int idx = 0;
    for (int k = 0; k < 4; ++k) {
        int c = 0;
        for (int j = k + 1; j < 5; ++j) c += (p[j] < p[k]) ? 1 : 0;
        idx += c * f[k];
    }
    return idx;
}

// Tables: cayley[a][b] = idx(perm_a o perm_b); fpt[v] = featperm[v];
// s4list (perms fixing position 4); crep (transpositions (i 4)); ubycoset; misc.
__global__ void build_tables(const float* __restrict__ eq_bias,
                             const float* __restrict__ Wout,
                             const float* __restrict__ bout,
                             int* __restrict__ cayley, int* __restrict__ fpt,
                             int* __restrict__ s4list, int* __restrict__ crep,
                             int* __restrict__ ubycoset, float* __restrict__ misc) {
    __shared__ int perms[GG][5];
    __shared__ int invp[GG];
    int t = threadIdx.x;   // 128
    if (t < GG) {
        int p[5]; idx_to_perm(t, p);
        for (int k = 0; k < 5; ++k) perms[t][k] = p[k];
        int q[5];
        for (int k = 0; k < 5; ++k) q[p[k]] = k;
        invp[t] = perm_to_idx(q);
    }
    __syncthreads();
    if (t < GG) {
        // F(perms[t]) row -> fpt[invp[t]]  (fpt[v] = F(v^-1) = featperm[v])
        int dst = invp[t];
        for (int r = 0; r < QF; ++r) {
            int v = r & 32;
            for (int k = 0; k < 5; ++k) {
                int bit = (r >> (4 - perms[t][k])) & 1;
                v |= bit << (4 - k);
            }
            fpt[dst * QF + r] = v;
        }
        // cayley row t
        for (int b = 0; b < GG; ++b) {
            int comp[5];
            for (int k = 0; k < 5; ++k) comp[k] = perms[t][perms[b][k]];
            cayley[t * GG + b] = perm_to_idx(comp);
        }
    }
    __syncthreads();
    if (t == 0) {
        int n4 = 0;
        for (int p = 0; p < GG; ++p)
            if (perms[p][4] == 4) s4list[n4++] = p;
        for (int i = 0; i < 5; ++i) {
            int c[5] = {0, 1, 2, 3, 4};
            c[i] = 4; c[4] = i;               // i=4 -> identity
            crep[i] = perm_to_idx(c);
        }
        int cnt[NACT];
        for (int a = 0; a < NACT; ++a) cnt[a] = 0;
        for (int p = 0; p < GG; ++p) {
            int a0 = perms[p][0], a1 = perms[p][1];
            int a = a0 * 4 + (a1 > a0 ? a1 - 1 : a1);
            ubycoset[a * 6 + cnt[a]++] = p;
        }
    }
    // misc (all 128 threads)
    {
        float s = 0.f;
        for (int g = 0; g < GG; ++g) s += eq_bias[g * HID + t];
        misc[t] = s * (1.f / GG);
        float w = 0.f;
        for (int n = 0; n < NACT; ++n) w += Wout[t * NACT + n];
        misc[HID + t] = w * (1.f / NACT);
        if (t == 0) {
            float c = 0.f;
            for (int n = 0; n < NACT; ++n) c += bout[n];
            misc[2 * HID] = c * (1.f / NACT);
        }
    }
}

// split x and W1^T into bf16 hi/lo (one kernel, branch on block)
__global__ void split_inputs(const float* __restrict__ x,
                             const float* __restrict__ W1,
                             unsigned short* __restrict__ xh,
                             unsigned short* __restrict__ xl,
                             unsigned short* __restrict__ w1th,
                             unsigned short* __restrict__ w1tl) {
    int bid = blockIdx.x;
    if (bid < 512) {
        int i = bid * 256 + threadIdx.x;           // < 131072
        float f = x[i];
        unsigned short h = f2bf(f);
        xh[i] = h;
        xl[i] = f2bf(f - bf2f(h));
    } else {
        int i = (bid - 512) * 256 + threadIdx.x;   // < 16384
        int k = i >> 7, n = i & 127;
        float f = W1[i];                           // W1[k][n]
        unsigned short h = f2bf(f);
        w1th[n * HID + k] = h;
        w1tl[n * HID + k] = f2bf(f - bf2f(h));
    }
}

// Stage 1: A[y][r'][h] = sum_{s in S4} eqw[s*y][fpt[s][r']][h]
__global__ void weff_stage1(const float* __restrict__ eqw,
                            const int* __restrict__ cayley,
                            const int* __restrict__ fpt,
                            const int* __restrict__ s4list,
                            float* __restrict__ Abuf) {
    int y = blockIdx.x;                       // 0..119
    int h = blockIdx.y * 32 + (threadIdx.x & 31);
    int rg = threadIdx.x >> 5;                // 0..7
    float acc[8];
#pragma unroll
    for (int rr = 0; rr < 8; ++rr) acc[rr] = 0.f;
    for (int si = 0; si < 24; ++si) {
        int s = s4list[si];
        int g = cayley[s * GG + y];
        const float* src = eqw + (unsigned)(g * QF) * HID + h;
        const int* fp = fpt + s * QF + rg * 8;
#pragma unroll
        for (int rr = 0; rr < 8; ++rr)
            acc[rr] += src[fp[rr] * HID];
    }
    float* dst = Abuf + (unsigned)(y * QF + rg * 8) * HID + h;
#pragma unroll
    for (int rr = 0; rr < 8; ++rr) dst[rr * HID] = acc[rr];
}

// Stage 2: Weff[u][r][h] = (1/G) sum_i A[cayley[crep[i]][u]][fpt[crep[i]][r]][h];
// transpose to [u][h][r], split bf16 hi/lo.
__global__ void weff_stage2(const float* __restrict__ Abuf,
                            const int* __restrict__ cayley,
                            const int* __restrict__ fpt,
                            const int* __restrict__ crep,
                            unsigned short* __restrict__ weffh,
                            unsigned short* __restrict__ weffl) {
    __shared__ float Wacc[QF][HID];   // 32 KB
    int u = blockIdx.x;
    int h = threadIdx.x & 127, rg = threadIdx.x >> 7;   // rg 0/1
    for (int rr = 0; rr < 32; ++rr) {
        int r = rg * 32 + rr;
        float s = 0.f;
#pragma unroll
        for (int i = 0; i < 5; ++i) {
            int ci = crep[i];
            int y = cayley[ci * GG + u];
            int rp = fpt[ci * QF + r];
            s += Abuf[(unsigned)(y * QF + rp) * HID + h];
        }
        Wacc[r][h] = s * (1.f / GG);
    }
    __syncthreads();
    int h2 = threadIdx.x >> 1, half = threadIdx.x & 1;
    unsigned short* dh = weffh + (unsigned)(u * HID + h2) * QF + half * 32;
    unsigned short* dl = weffl + (unsigned)(u * HID + h2) * QF + half * 32;
#pragma unroll
    for (int c8 = 0; c8 < 4; ++c8) {
        ushort8 vh, vl;
#pragma unroll
        for (int j = 0; j < 8; ++j) {
            float f = Wacc[half * 32 + c8 * 8 + j][h2];
            unsigned short hh = f2bf(f);
            vh[j] = hh;
            vl[j] = f2bf(f - bf2f(hh));
        }
        *(ushort8*)(dh + c8 * 8) = vh;
        *(ushort8*)(dl + c8 * 8) = vl;
    }
}

#define XS_STR 72    // ushort stride (144 B)
#define HB_STR 136   // ushort stride (272 B)
#define UCHUNK 4
#define NCH    30    // 120/UCHUNK

__device__ __forceinline__ void mlp_body(
    int u, int un, int lm, int kg, int tid, int colbase, int rowbase,
    const float (&bm)[2], const float (&b1v)[2], const float (&wmv)[2],
    f32x4 (&wcur)[2][2][2], f32x4 (&wnext)[2][2][2],
    const unsigned short* __restrict__ weffh,
    const unsigned short* __restrict__ weffl,
    const f32x4 (&w1f)[2][4][2],
    const unsigned short* xsH, const unsigned short* xsL,
    unsigned short* hbH, unsigned short* hbL,
    float (*msum)[4], float* __restrict__ m) {
    int w = tid >> 6;
    // ---- stage A: E[64][32-slice] = X @ Weff[u] ----
    f32x4 acc[4][2];
#pragma unroll
    for (int mt = 0; mt < 4; ++mt)
#pragma unroll
        for (int nt = 0; nt < 2; ++nt) acc[mt][nt] = (f32x4){0.f, 0.f, 0.f, 0.f};
#pragma unroll
    for (int mt = 0; mt < 4; ++mt) {
#pragma unroll
        for (int ks = 0; ks < 2; ++ks) {
            bf16x8 ah = *(const bf16x8*)(xsH + (mt * 16 + lm) * XS_STR + ks * 32 + kg * 8);
            bf16x8 al = *(const bf16x8*)(xsL + (mt * 16 + lm) * XS_STR + ks * 32 + kg * 8);
#pragma unroll
            for (int nt = 0; nt < 2; ++nt) {
                bf16x8 bh = __builtin_bit_cast(bf16x8, wcur[nt][ks][0]);
                bf16x8 bl = __builtin_bit_cast(bf16x8, wcur[nt][ks][1]);
                acc[mt][nt] = __builtin_amdgcn_mfma_f32_16x16x32_bf16(ah, bh, acc[mt][nt], 0, 0, 0);
                acc[mt][nt] = __builtin_amdgcn_mfma_f32_16x16x32_bf16(ah, bl, acc[mt][nt], 0, 0, 0);
                acc[mt][nt] = __builtin_amdgcn_mfma_f32_16x16x32_bf16(al, bh, acc[mt][nt], 0, 0, 0);
            }
        }
    }
    // ---- prefetch next u's Weff fragments into wnext ----
    if (un >= 0) {
        const unsigned short* whp = weffh + (unsigned)(un * HID) * QF;
        const unsigned short* wlp = weffl + (unsigned)(un * HID) * QF;
#pragma unroll
        for (int nt = 0; nt < 2; ++nt)
#pragma unroll
            for (int ks = 0; ks < 2; ++ks) {
                int off = (colbase + nt * 16 + lm) * QF + ks * 32 + kg * 8;
                wnext[nt][ks][0] = *(const f32x4*)(whp + off);
                wnext[nt][ks][1] = *(const f32x4*)(wlp + off);
                keepv(wnext[nt][ks][0]);
                keepv(wnext[nt][ks][1]);
            }
    }
    // ---- epilogue A: relu(e+bmean), split hi/lo -> hb ----
#pragma unroll
    for (int mt = 0; mt < 4; ++mt)
#pragma unroll
        for (int nt = 0; nt < 2; ++nt) {
            int col = colbase + nt * 16 + lm;
#pragma unroll
            for (int r = 0; r < 4; ++r) {
                int row = mt * 16 + kg * 4 + r;
                float e = acc[mt][nt][r] + bm[nt];
                e = e > 0.f ? e : 0.f;
                unsigned short eh = f2bf(e);
                unsigned short el = f2bf(e - bf2f(eh));
                hbH[row * HB_STR + col] = eh;
                hbL[row * HB_STR + col] = el;
            }
        }
    __syncthreads();
    // ---- stage B: H2 = relu(E) @ W1 (W1 frags register-pinned) ----
    f32x4 acc2[4][2];
#pragma unroll
    for (int mt = 0; mt < 4; ++mt)
#pragma unroll
        for (int nt = 0; nt < 2; ++nt) acc2[mt][nt] = (f32x4){0.f, 0.f, 0.f, 0.f};
#pragma unroll
    for (int mt = 0; mt < 4; ++mt) {
#pragma unroll
        for (int ks = 0; ks < 4; ++ks) {
            bf16x8 ah = *(const bf16x8*)(hbH + (mt * 16 + lm) * HB_STR + ks * 32 + kg * 8);
            bf16x8 al = *(const bf16x8*)(hbL + (mt * 16 + lm) * HB_STR + ks * 32 + kg * 8);
#pragma unroll
            for (int nt = 0; nt < 2; ++nt) {
                bf16x8 bh = __builtin_bit_cast(bf16x8, w1f[nt][ks][0]);
                bf16x8 bl = __builtin_bit_cast(bf16x8, w1f[nt][ks][1]);
                acc2[mt][nt] = __builtin_amdgcn_mfma_f32_16x16x32_bf16(ah, bh, acc2[mt][nt], 0, 0, 0);
                acc2[mt][nt] = __builtin_amdgcn_mfma_f32_16x16x32_bf16(ah, bl, acc2[mt][nt], 0, 0, 0);
                acc2[mt][nt] = __builtin_amdgcn_mfma_f32_16x16x32_bf16(al, bh, acc2[mt][nt], 0, 0, 0);
            }
        }
    }
    // ---- epilogue B: relu(h2+b1).wmean, 16-lane reduce, cross-wave via msum ----
    float ps[4][4];
#pragma unroll
    for (int mt = 0; mt < 4; ++mt)
#pragma unroll
        for (int r = 0; r < 4; ++r) {
            float s = 0.f;
#pragma unroll
            for (int nt = 0; nt < 2; ++nt) {
                float v = acc2[mt][nt][r] + b1v[nt];
                v = v > 0.f ? v : 0.f;
                s += v * wmv[nt];
            }
            ps[mt][r] = s;
        }
#pragma unroll
    for (int off = 1; off < 16; off <<= 1)
#pragma unroll
        for (int mt = 0; mt < 4; ++mt)
#pragma unroll
            for (int r = 0; r < 4; ++r) ps[mt][r] += __shfl_xor(ps[mt][r], off);
    if (lm == 0) {
#pragma unroll
        for (int mt = 0; mt < 4; ++mt)
#pragma unroll
            for (int r = 0; r < 4; ++r)
                msum[mt * 16 + kg * 4 + r][w] = ps[mt][r];
    }
    __syncthreads();
    if (tid < 64) {
        float s = msum[tid][0] + msum[tid][1] + msum[tid][2] + msum[tid][3];
        m[(unsigned)(u * BTOT) + rowbase + tid] = s;
    }
}

__global__ __launch_bounds__(256, 2)
void mlp_mfma(const unsigned short* __restrict__ xh,
              const unsigned short* __restrict__ xl,
              const unsigned short* __restrict__ weffh,
              const unsigned short* __restrict__ weffl,
              const unsigned short* __restrict__ w1th,
              const unsigned short* __restrict__ w1tl,
              const float* __restrict__ b1,
              const float* __restrict__ misc,
              float* __restrict__ m) {
    __shared__ __align__(16) unsigned short xsH[64 * XS_STR];
    __shared__ __align__(16) unsigned short xsL[64 * XS_STR];
    __shared__ __align__(16) unsigned short hbH[64 * HB_STR];
    __shared__ __align__(16) unsigned short hbL[64 * HB_STR];
    __shared__ float msum[64][4];

    int bid = blockIdx.x;
    int uc = bid % NCH, tile = bid / NCH;
    int u0 = uc * UCHUNK;
    int rowbase = tile * 64;

    int tid = threadIdx.x;
    int lane = tid & 63;
    int lm = lane & 15, kg = lane >> 4;
    int colbase = (tid >> 6) * 32;

    float bm[2]  = {misc[colbase + lm], misc[colbase + 16 + lm]};
    float b1v[2] = {b1[colbase + lm], b1[colbase + 16 + lm]};
    float wmv[2] = {misc[HID + colbase + lm], misc[HID + colbase + 16 + lm]};

    // ---- W1 fragments: load once, pin in VGPRs ----
    f32x4 w1f[2][4][2];
#pragma unroll
    for (int nt = 0; nt < 2; ++nt)
#pragma unroll
        for (int ks = 0; ks < 4; ++ks) {
            int off = (colbase + nt * 16 + lm) * HID + ks * 32 + kg * 8;
            w1f[nt][ks][0] = *(const f32x4*)(w1th + off);
            w1f[nt][ks][1] = *(const f32x4*)(w1tl + off);
            keepv(w1f[nt][ks][0]);
            keepv(w1f[nt][ks][1]);
        }

    // ---- X tile -> LDS (once per block, reused across UCHUNK u's) ----
    const unsigned short* xhp = xh + (unsigned)rowbase * QF;
    const unsigned short* xlp = xl + (unsigned)rowbase * QF;
#pragma unroll
    for (int i = tid; i < 64 * 8; i += 256) {
        int row = i >> 3, c8 = (i & 7) * 8;
        *(ushort8*)(xsH + row * XS_STR + c8) = *(const ushort8*)(xhp + row * QF + c8);
        *(ushort8*)(xsL + row * XS_STR + c8) = *(const ushort8*)(xlp + row * QF + c8);
    }

    // ---- Weff fragments for u0 ----
    f32x4 wefA[2][2][2], wefB[2][2][2];
    {
        const unsigned short* whp = weffh + (unsigned)(u0 * HID) * QF;
        const unsigned short* wlp = weffl + (unsigned)(u0 * HID) * QF;
#pragma unroll
        for (int nt = 0; nt < 2; ++nt)
#pragma unroll
            for (int ks = 0; ks < 2; ++ks) {
                int off = (colbase + nt * 16 + lm) * QF + ks * 32 + kg * 8;
                wefA[nt][ks][0] = *(const f32x4*)(whp + off);
                wefA[nt][ks][1] = *(const f32x4*)(wlp + off);
                keepv(wefA[nt][ks][0]);
                keepv(wefA[nt][ks][1]);
            }
    }
    __syncthreads();

#pragma unroll 1
    for (int ui = 0; ui < UCHUNK; ui += 2) {
        int u = u0 + ui;
        mlp_body(u, u + 1, lm, kg, tid, colbase, rowbase, bm, b1v, wmv,
                 wefA, wefB, weffh, weffl, w1f, xsH, xsL, hbH, hbL, msum, m);
        int un2 = (ui + 2 < UCHUNK) ? (u + 2) : -1;
        mlp_body(u + 1, un2, lm, kg, tid, colbase, rowbase, bm, b1v, wmv,
                 wefB, wefA, weffh, weffl, w1f, xsH, xsL, hbH, hbL, msum, m);
    }
}

__global__ void reduce_out(const float* __restrict__ m,
                           const int* __restrict__ ubycoset,
                           const float* __restrict__ misc,
                           float* __restrict__ out) {
    int idx = blockIdx.x * 256 + threadIdx.x;   // bt*20 + a
    if (idx >= BTOT * NACT) return;
    int bt = idx / NACT, a = idx % NACT;
    float s = 0.f;
#pragma unroll
    for (int j = 0; j < 6; ++j) s += m[ubycoset[a * 6 + j] * BTOT + bt];
    out[idx] = s * (1.f / 6.f) + misc[2 * HID];
}

extern "C" void kernel_launch(void* const* d_in, const int* in_sizes, int n_in,
                              void* d_out, int out_size, void* d_ws, size_t ws_size,
                              hipStream_t stream) {
    const float* x       = (const float*)d_in[0];
    const float* eqw     = (const float*)d_in[1];
    const float* eq_bias = (const float*)d_in[2];
    const float* W1      = (const float*)d_in[3];
    const float* b1      = (const float*)d_in[4];
    const float* Wout    = (const float*)d_in[5];
    const float* bout    = (const float*)d_in[6];
    float* out           = (float*)d_out;

    char* ws = (char*)d_ws;
    unsigned short* weffh = (unsigned short*)(ws + WEFFH_OFF);
    unsigned short* weffl = (unsigned short*)(ws + WEFFL_OFF);
    unsigned short* xhb   = (unsigned short*)(ws + XH_OFF);
    unsigned short* xlb   = (unsigned short*)(ws + XL_OFF);
    unsigned short* w1th  = (unsigned short*)(ws + W1TH_OFF);
    unsigned short* w1tl  = (unsigned short*)(ws + W1TL_OFF);
    float* misc   = (float*)(ws + MISC_OFF);
    int* cayley   = (int*)(ws + CAYL_OFF);
    int* fpt      = (int*)(ws + FPT_OFF);
    int* s4list   = (int*)(ws + S4_OFF);
    int* crep     = (int*)(ws + CREP_OFF);
    int* ubycoset = (int*)(ws + UBYC_OFF);
    float* Abuf   = (float*)(ws + ABUF_OFF);
    float* mbuf   = (float*)(ws + M_OFF);     // aliases Abuf (Abuf dead by mlp)

    hipLaunchKernelGGL(build_tables, dim3(1), dim3(128), 0, stream,
                       eq_bias, Wout, bout, cayley, fpt, s4list, crep, ubycoset, misc);
    hipLaunchKernelGGL(split_inputs, dim3(576), dim3(256), 0, stream,
                       x, W1, xhb, xlb, w1th, w1tl);
    hipLaunchKernelGGL(weff_stage1, dim3(120, 4), dim3(256), 0, stream,
                       eqw, cayley, fpt, s4list, Abuf);
    hipLaunchKernelGGL(weff_stage2, dim3(120), dim3(256), 0, stream,
                       Abuf, cayley, fpt, crep, weffh, weffl);
    hipLaunchKernelGGL(mlp_mfma, dim3(32 * NCH), dim3(256), 0, stream,
                       xhb, xlb, weffh, weffl, w1th, w1tl, b1, misc, mbuf);
    hipLaunchKernelGGL(reduce_out, dim3((BTOT * NACT + 255) / 256), dim3(256), 0, stream,
                       mbuf, ubycoset, misc, out);
}